// Round 12
// baseline (359.610 us; speedup 1.0000x reference)
//
#include <hip/hip_runtime.h>
#include <hip/hip_bf16.h>
#include <math.h>

typedef unsigned long long u64;
typedef short short8v __attribute__((ext_vector_type(8)));   // 8 bf16 (4 VGPR)
typedef float f32x4 __attribute__((ext_vector_type(4)));

// ===========================================================================
// k_prep: ALL parameter preprocessing in one kernel.
//  R0 (gid<R1): wave-per-word sign pack, 7 segments:
//     5 psum stages -> combined wlut (stride-4 slots 0,1 = {w0,w1}),
//     fc2 -> transposed [16][1024], fc3 -> plain [10][16]
//  R1..R2: fc1 pack -> transposed [128][1024], channel-major bit layout
//  R2..R3: LSQ deltas {dp,dn} into wlut slots 2,3 (exact f64, reference
//     expression order; saturation of |isum|>=2 guaranteed by alpha range)
//  R3..R4: CZ[o] = sum_s cz(s,o) ascending-s (exact f64)
//  R4..R5: bf16 MFMA B-fragments (+-1.0 bf16) for stages s2,s4,s6:
//     frag fi=(s*NOCb+oc)*4+kc, thread lt=fi*64+ln writes 8 ushorts at lt*8;
//     o = oc*16+(ln&15), k = kc*32+(ln>>4)*8+e  (same k-convention as A side)
// ===========================================================================
struct PrepArgs {
    const float* w[7];
    u64* out[7];
    int cnt[7];
    int mode[7];    // 0 plain, 1 stage-combined, 2 fc2T
    const float* fc1w;
    u64* fc1T;
    const float* alpha[5];
    const float* bias[5];
    int loff[5];    // {0,1152,3456,8064,17280}
    int lCout[5];
    double gq[5];
    u64* wlut;
    double* czv;
    int czoff[5];   // {0,128,384,640,1152}
    int czS[5];
    const float* msw[3];
    ushort* mwbf[3];
    int mCout[3];
    int mS[3];
    int mtoff[3];   // {0,18432,92160}
    int R1, R2, R3, R4, R5;
};

__global__ __launch_bounds__(256)
void k_prep(PrepArgs A) {
    int gid = blockIdx.x * 256 + threadIdx.x;
    int lane = threadIdx.x & 63;
    if (gid < A.R1) {
        int wid = gid >> 6;
        int seg = 0, base = 0, pre = 0;
#pragma unroll
        for (int t = 0; t < 7; ++t) {
            if (wid >= pre) { seg = t; base = pre; }
            pre += A.cnt[t];
        }
        int li = wid - base;
        const float* p = A.w[seg] + ((size_t)li << 6);
        u64 m = __ballot(p[lane] > 0.f);
        if (lane == 0) {
            int mode = A.mode[seg];
            size_t idx = (mode == 1) ? ((size_t)(li >> 1) * 4 + (li & 1))
                       : (mode == 2) ? ((size_t)(li & 15) * 1024 + (li >> 4))
                       : (size_t)li;
            A.out[seg][idx] = m;
        }
    } else if (gid < A.R2) {
        int wid = (gid - A.R1) >> 6;
        int row = wid >> 3, gk = wid & 7;
        int g = gk >> 1, k = gk & 1;
        int c = g * 128 + k * 64 + lane;
        const float* p = A.fc1w + (size_t)row * 8192 + (size_t)c * 16;
        float arr[16];
#pragma unroll
        for (int q = 0; q < 4; ++q) {
            float4 f = ((const float4*)p)[q];
            arr[4 * q + 0] = f.x; arr[4 * q + 1] = f.y;
            arr[4 * q + 2] = f.z; arr[4 * q + 3] = f.w;
        }
#pragma unroll
        for (int h = 0; h < 4; ++h)
#pragma unroll
        for (int xq = 0; xq < 4; ++xq) {
            u64 m = __ballot(arr[h * 4 + xq] > 0.f);
            if (lane == 0) {
                int wd = g * 32 + h * 8 + xq * 2 + k;
                A.fc1T[(size_t)wd * 1024 + row] = m;
            }
        }
    } else if (gid < A.R3) {
        int idx = gid - A.R2;
        int seg = 0;
#pragma unroll
        for (int t = 1; t < 5; ++t) if (idx >= A.loff[t]) seg = t;
        int li = idx - A.loff[seg];
        int s = li / A.lCout[seg];
        double al = (double)A.alpha[seg][s];
        double tg = al * A.gq[seg];
        double a  = tg + (al - tg);
        double b  = (double)A.bias[seg][li];
        double q0 = rint(fmin(fmax(b / a, -4.0), 3.0));
        double qp = rint(fmin(fmax((2.0 + b) / a, -4.0), 3.0));
        double qn = rint(fmin(fmax((-2.0 + b) / a, -4.0), 3.0));
        double cz = q0 * a;
        A.wlut[(size_t)idx * 4 + 2] = __double_as_longlong(qp * a - cz);
        A.wlut[(size_t)idx * 4 + 3] = __double_as_longlong(qn * a - cz);
    } else if (gid < A.R4) {
        int idx = gid - A.R3;
        int seg = 0;
#pragma unroll
        for (int t = 1; t < 5; ++t) if (idx >= A.czoff[t]) seg = t;
        int o = idx - A.czoff[seg];
        int Cout = A.lCout[seg];
        double CZ = 0.0;
        for (int s = 0; s < A.czS[seg]; ++s) {
            double al = (double)A.alpha[seg][s];
            double tg = al * A.gq[seg];
            double a  = tg + (al - tg);
            double b  = (double)A.bias[seg][s * Cout + o];
            double q0 = rint(fmin(fmax(b / a, -4.0), 3.0));
            CZ += q0 * a;
        }
        A.czv[idx] = CZ;
    } else if (gid < A.R5) {
        int t = gid - A.R4;
        int ms = 0;
#pragma unroll
        for (int t2 = 1; t2 < 3; ++t2) if (t >= A.mtoff[t2]) ms = t2;
        int lt = t - A.mtoff[ms];
        int ln = lt & 63;
        int fi = lt >> 6;
        int kc = fi & 3;
        int rest = fi >> 2;
        int Cs = A.mCout[ms];
        int NOCb = Cs >> 4;
        int oc = rest % NOCb;
        int s = rest / NOCb;
        int o = oc * 16 + (ln & 15);
        int kb = kc * 32 + (ln >> 4) * 8;
        const float* wp = A.msw[ms] + ((size_t)s * Cs + o) * 128 + kb;
        u64 lo = 0, hi = 0;
#pragma unroll
        for (int e = 0; e < 4; ++e) {
            u64 v0 = (wp[e] > 0.f) ? 0x3F80ull : 0xBF80ull;
            u64 v1 = (wp[4 + e] > 0.f) ? 0x3F80ull : 0xBF80ull;
            lo |= v0 << (16 * e);
            hi |= v1 << (16 * e);
        }
        ulonglong2 st; st.x = lo; st.y = hi;
        *(ulonglong2*)(A.mwbf[ms] + (size_t)lt * 8) = st;
    }
}

// ===========================================================================
// conv1 (3->128, 3x3, pad 1) + bias + bn1 affine -> packed sign bits.
// ===========================================================================
__global__ __launch_bounds__(128)
void k_conv1(const float* __restrict__ x, const float* __restrict__ w,
             const float* __restrict__ cb, const float* __restrict__ g1,
             const float* __restrict__ b1, u64* __restrict__ apack) {
    __shared__ double xs[3][3][34];
    int h = blockIdx.x & 31;
    int b = blockIdx.x >> 5;
    int tid = threadIdx.x;
    for (int idx = tid; idx < 306; idx += 128) {
        int dyy = idx / 102;
        int rem = idx - dyy * 102;
        int ci = rem / 34;
        int col = rem - ci * 34;
        int y = h + dyy - 1, xx = col - 1;
        double v = 0.0;
        if ((unsigned)y < 32u && (unsigned)xx < 32u)
            v = (double)x[((b * 3 + ci) * 32 + y) * 32 + xx];
        xs[dyy][ci][col] = v;
    }
    __syncthreads();
    int o = tid;
    double sg[3][3][3];
#pragma unroll
    for (int ci = 0; ci < 3; ++ci)
#pragma unroll
    for (int ky = 0; ky < 3; ++ky)
#pragma unroll
    for (int kx = 0; kx < 3; ++kx) {
        float wv = w[o * 27 + (ci * 3 + ky) * 3 + kx];
        sg[kx][ci][ky] = wv > 0.f ? 1.0 : (wv < 0.f ? -1.0 : 0.0);
    }
    double cbv = (double)cb[o], g1v = (double)g1[o], b1v = (double)b1[o];
    double A0 = 0.0, A1 = 0.0, A2 = 0.0;
    for (int pc = 0; pc < 34; ++pc) {
        double v[3][3];
#pragma unroll
        for (int ky = 0; ky < 3; ++ky)
#pragma unroll
        for (int ci = 0; ci < 3; ++ci)
            v[ky][ci] = xs[ky][ci][pc];
        A2 = 0.0;
#pragma unroll
        for (int ci = 0; ci < 3; ++ci)
#pragma unroll
        for (int ky = 0; ky < 3; ++ky) {
            A0 += v[ky][ci] * sg[2][ci][ky];
            A1 += v[ky][ci] * sg[1][ci][ky];
            A2 += v[ky][ci] * sg[0][ci][ky];
        }
        if (pc >= 2) {
            int wc = pc - 2;
            double t = (A0 + cbv) * g1v + b1v;
            u64 m = __ballot(t > 0.0);
            if ((tid & 63) == 0)
                apack[((size_t)(b * 1024 + h * 32 + wc)) * 2 + (tid >> 6)] = m;
        }
        A0 = A1; A1 = A2;
    }
}

// ===========================================================================
// VALU psum-stage (proven round-4 form, absmax 0.0 @ 221.9us) for s3/s5.
// ===========================================================================
template <int POOL, int G, int H, int W, int Cout, int OCH, int NCH, int CWP>
__global__ __launch_bounds__(POOL * OCH)
void k_stage_v(const u64* __restrict__ apack, const u64* __restrict__ wlut,
               const double* __restrict__ czv,
               const float* __restrict__ gam, const float* __restrict__ bet,
               u64* __restrict__ opack) {
    constexpr int Ho = H / POOL, Wo = W / POOL;
    constexpr int NOC = Cout / OCH;
    constexpr int CRAW = NCH * CWP * POOL;
    constexpr int NROW = POOL + 2;
    constexpr int NCOL = CRAW + 2;
    constexpr int NT = POOL * OCH;
    constexpr int CB = Wo / (NCH * CWP);
    __shared__ alignas(16) u64 sact[G][NROW][NCOL][2];

    int bi = blockIdx.x;
    int oc = bi % NOC; bi /= NOC;
    int cb = bi % CB;  bi /= CB;
    int ph = bi % Ho;
    int b  = bi / Ho;
    int tid = threadIdx.x;
    int ch = tid / OCH;                 // wave-uniform (OCH % 64 == 0)
    int ol = tid - ch * OCH;
    int o  = oc * OCH + ol;
    int colb = cb * CRAW;
    int c0 = colb + ch * CWP * POOL;
    int ybase = ph * POOL - 1;

    for (int t = tid; t < G * NROW * NCOL; t += NT) {
        int g = t / (NROW * NCOL);
        int rr = t - g * (NROW * NCOL);
        int yy = rr / NCOL;
        int xx = rr - yy * NCOL;
        int y = ybase + yy, x = colb - 1 + xx;
        u64 v0 = 0, v1 = 0;
        if ((unsigned)y < (unsigned)H && (unsigned)x < (unsigned)W) {
            const u64* p = apack + (((size_t)((b * G + g) * H + y)) * W + x) * 2;
            v0 = p[0]; v1 = p[1];
        }
        sact[g][yy][xx][0] = v0;
        sact[g][yy][xx][1] = v1;
    }
    __syncthreads();

    double CZ = czv[o];
    double acc[CWP * POOL * POOL];
#pragma unroll
    for (int k = 0; k < CWP * POOL * POOL; ++k) acc[k] = CZ;

    const bool lo0 = (c0 == 0);
    const bool hiW = (c0 + CWP * POOL == W);

#pragma unroll
    for (int g = 0; g < G; ++g) {
#pragma unroll
        for (int j = 0; j < 3; ++j) {
#pragma unroll
            for (int i = 0; i < 3; ++i) {
                const int s = g * 9 + j * 3 + i;
                size_t so = (size_t)s * Cout + o;
                const u64* wl = wlut + so * 4;
                u64 w0 = wl[0], w1 = wl[1];
                double dp = __longlong_as_double(wl[2]);
                double dn = __longlong_as_double(wl[3]);
#pragma unroll
                for (int dy = 0; dy < POOL; ++dy) {
                    int y = ph * POOL + dy + i - 1;
                    if ((unsigned)y >= (unsigned)H) continue;   // cz, in CZ
                    const int yy = dy + i;
#pragma unroll
                    for (int cc = 0; cc < CWP * POOL; ++cc) {
                        if (cc == 0 && j == 0 && lo0) continue;
                        if (cc == CWP * POOL - 1 && j == 2 && hiW) continue;
                        int xx = ch * CWP * POOL + cc + j;
                        u64 a0 = sact[g][yy][xx][0];
                        u64 a1 = sact[g][yy][xx][1];
                        int d = __popcll(a0 ^ w0) + __popcll(a1 ^ w1);
                        double val = (d < 64) ? dp : dn;
                        val = (d == 64) ? 0.0 : val;
                        acc[cc * POOL + dy] += val;
                    }
                }
            }
        }
    }

    double gv = (double)gam[o], bv = (double)bet[o];
#pragma unroll
    for (int cw = 0; cw < CWP; ++cw) {
        double m;
        if constexpr (POOL == 1) {
            m = acc[cw];
        } else {
            m = fmax(fmax(acc[(cw * 2 + 0) * 2 + 0], acc[(cw * 2 + 0) * 2 + 1]),
                     fmax(acc[(cw * 2 + 1) * 2 + 0], acc[(cw * 2 + 1) * 2 + 1]));
        }
        double tt = m * gv + bv;
        u64 bm = __ballot(tt > 0.0);
        if ((tid & 63) == 0) {
            int pw = c0 / POOL + cw;
            opack[(((size_t)(b * (Cout >> 7) + (o >> 7)) * Ho + ph) * Wo + pw) * 2
                  + ((o >> 6) & 1)] = bm;
        }
    }
}

// ===========================================================================
// MFMA psum-stage (POOL=2 stages s2/s4/s6) + maxpool + BN + sign-pack.
// Block = (b, 2-row band, 128-o group), 512 thr. Bits -> +-1 bf16 LDS image
// (pad rows/cols stored as 0.0 -> isum==0 class automatically, no pv fixup).
// Channel index XOR-swizzled by (x&7)<<3 (ushort units) for bank-free b128.
// Per wave-task (2x8-pixel strip, 16-o chunk) loop slices s ascending:
// 4 chained mfma_f32_16x16x32_bf16 -> EXACT isum per 16(pixel)x16(o) tile;
// per lane 4 f64 select-adds (isum>0:dp, <0:dn, ==0:0) into acc=CZ[o].
// C/D: row(pixel)=(lane>>4)*4+reg, col(o)=lane&15 [HW-verified m89/m91].
// A supplies row m=lane&15, k=(lane>>4)*8+e; B col n=lane&15 same k-map.
// ===========================================================================
template <int G, int H, int W, int Cout>
__global__ __launch_bounds__(512)
void k_stage_m(const u64* __restrict__ apack, const ushort* __restrict__ wbf,
               const u64* __restrict__ wlut, const double* __restrict__ czv,
               const float* __restrict__ gam, const float* __restrict__ bet,
               u64* __restrict__ opack) {
    constexpr int NOCb = Cout / 16;
    constexpr int OGRPS = Cout / 128;
    constexpr int STRIPS = W / 8;
    constexpr int TASKS = STRIPS * 8;
    constexpr int TPW = TASKS / 8;
    constexpr int BANDS = H / 2;
    constexpr int WP2 = W + 2;
    constexpr int PIX = W / 2;
    constexpr int Ho = H / 2, Wo = W / 2;

    __shared__ alignas(16) ushort img[G][4][WP2][128];
    __shared__ alignas(16) unsigned char sgn[PIX][128];

    int bi = blockIdx.x;
    int ogrp = bi % OGRPS; bi /= OGRPS;
    int band = bi % BANDS;
    int b = bi / BANDS;
    int tid = threadIdx.x;
    int lane = tid & 63;
    int wid = tid >> 6;

    // ---- unpack bits -> bf16 image (zero borders) ----
    for (int cell = tid; cell < G * 4 * WP2; cell += 512) {
        int g = cell / (4 * WP2);
        int r2 = cell - g * (4 * WP2);
        int yy = r2 / WP2;
        int xx = r2 - yy * WP2;
        int y = band * 2 + yy - 1;
        int xg = xx - 1;
        u64 a0 = 0, a1 = 0;
        bool ok = ((unsigned)y < (unsigned)H) && ((unsigned)xg < (unsigned)W);
        if (ok) {
            const u64* p = apack + ((size_t)((b * G + g) * H + y) * W + xg) * 2;
            a0 = p[0]; a1 = p[1];
        }
        char* cp = (char*)&img[g][yy][xx][0];
        int sw8 = (xx & 7) << 3;
#pragma unroll
        for (int p2 = 0; p2 < 32; ++p2) {
            unsigned lo = ok ? ((unsigned)((a0 >> (2 * p2)) & 1) ? 0x3F80u : 0xBF80u) : 0u;
            unsigned hi = ok ? ((unsigned)((a0 >> (2 * p2 + 1)) & 1) ? 0x3F80u : 0xBF80u) : 0u;
            *(unsigned*)(cp + (((2 * p2) ^ sw8) * 2)) = lo | (hi << 16);
        }
#pragma unroll
        for (int p2 = 0; p2 < 32; ++p2) {
            unsigned lo = ok ? ((unsigned)((a1 >> (2 * p2)) & 1) ? 0x3F80u : 0xBF80u) : 0u;
            unsigned hi = ok ? ((unsigned)((a1 >> (2 * p2 + 1)) & 1) ? 0x3F80u : 0xBF80u) : 0u;
            *(unsigned*)(cp + (((64 + 2 * p2) ^ sw8) * 2)) = lo | (hi << 16);
        }
    }
    __syncthreads();

#pragma unroll 1
    for (int tt = 0; tt < TPW; ++tt) {
        int task = wid * TPW + tt;
        int oc_l = task & 7;
        int strip = task >> 3;
        int oc = ogrp * 8 + oc_l;
        int n = lane & 15;
        int q = lane >> 4;
        int o = oc * 16 + n;
        int r = n >> 3;          // A-row pixel: raw row within band
        int cx = n & 7;          // A-row pixel: col within strip

        double CZ = czv[o];
        double acc0 = CZ, acc1 = CZ, acc2 = CZ, acc3 = CZ;

#pragma unroll 1
        for (int g = 0; g < G; ++g) {
#pragma unroll
            for (int j = 0; j < 3; ++j) {
#pragma unroll
                for (int i = 0; i < 3; ++i) {
                    int s = g * 9 + j * 3 + i;
                    size_t so = (size_t)s * Cout + o;
                    const ushort* wb = wbf + (((size_t)(s * NOCb + oc) * 4) * 64 + lane) * 8;
                    short8v b0 = *(const short8v*)(wb);
                    short8v b1 = *(const short8v*)(wb + 512);
                    short8v b2 = *(const short8v*)(wb + 1024);
                    short8v b3 = *(const short8v*)(wb + 1536);
                    int xx = strip * 8 + cx + j;
                    const ushort* cp = &img[g][r + i][xx][0];
                    int sw8 = (xx & 7) << 3;
                    short8v a0 = *(const short8v*)(cp + ((q * 8) ^ sw8));
                    short8v a1 = *(const short8v*)(cp + ((32 + q * 8) ^ sw8));
                    short8v a2 = *(const short8v*)(cp + ((64 + q * 8) ^ sw8));
                    short8v a3 = *(const short8v*)(cp + ((96 + q * 8) ^ sw8));
                    f32x4 c = {0.f, 0.f, 0.f, 0.f};
                    c = __builtin_amdgcn_mfma_f32_16x16x32_bf16(a0, b0, c, 0, 0, 0);
                    c = __builtin_amdgcn_mfma_f32_16x16x32_bf16(a1, b1, c, 0, 0, 0);
                    c = __builtin_amdgcn_mfma_f32_16x16x32_bf16(a2, b2, c, 0, 0, 0);
                    c = __builtin_amdgcn_mfma_f32_16x16x32_bf16(a3, b3, c, 0, 0, 0);
                    const u64* wl = wlut + so * 4;
                    double dp = __longlong_as_double(wl[2]);
                    double dn = __longlong_as_double(wl[3]);
                    float v0 = c[0], v1 = c[1], v2 = c[2], v3 = c[3];
                    double t0 = (v0 > 0.f) ? dp : dn; t0 = (v0 == 0.f) ? 0.0 : t0; acc0 += t0;
                    double t1 = (v1 > 0.f) ? dp : dn; t1 = (v1 == 0.f) ? 0.0 : t1; acc1 += t1;
                    double t2 = (v2 > 0.f) ? dp : dn; t2 = (v2 == 0.f) ? 0.0 : t2; acc2 += t2;
                    double t3 = (v3 > 0.f) ? dp : dn; t3 = (v3 == 0.f) ? 0.0 : t3; acc3 += t3;
                }
            }
        }

        // C row m = 4q+reg -> raw row m>>3, raw col strip*8 + (m&7).
        double gv = (double)gam[o], bv = (double)bet[o];
        double m0 = fmax(acc0, __shfl_xor(acc0, 32));   // row 0 vs row 1
        double m1 = fmax(acc1, __shfl_xor(acc1, 32));
        double m2 = fmax(acc2, __shfl_xor(acc2, 32));
        double m3 = fmax(acc3, __shfl_xor(acc3, 32));
        if (q < 2) {
            double p0 = fmax(m0, m1);                   // col pair -> pooled
            double p1 = fmax(m2, m3);
            int pw = strip * 4 + (q & 1) * 2;
            sgn[pw + 0][oc_l * 16 + n] = (p0 * gv + bv > 0.0) ? 1 : 0;
            sgn[pw + 1][oc_l * 16 + n] = (p1 * gv + bv > 0.0) ? 1 : 0;
        }
    }
    __syncthreads();

    // ---- pack sign bytes -> u64 bit words ----
    constexpr int WORDS = PIX * 2;
    for (int wt = wid; wt < WORDS; wt += 8) {
        int pix = wt >> 1;
        int wl = wt & 1;
        u64 bm = __ballot(sgn[pix][wl * 64 + lane] != 0);
        if (lane == 0) {
            int o_g = ogrp * 128 + wl * 64;
            int gout = o_g >> 7;
            int wsel = (o_g >> 6) & 1;
            opack[(((size_t)(b * (Cout >> 7) + gout) * Ho + band) * Wo + pix) * 2 + wsel] = bm;
        }
    }
}

// ===========================================================================
// Whole classifier in one kernel: block = one batch image (1024 threads).
// ===========================================================================
__global__ __launch_bounds__(1024)
void k_fc_all(const u64* __restrict__ abits, const u64* __restrict__ wf1T,
              const float* __restrict__ b1, const float* __restrict__ g1,
              const float* __restrict__ a1,
              const u64* __restrict__ wf2T,
              const float* __restrict__ b2, const float* __restrict__ g2,
              const float* __restrict__ a2,
              const u64* __restrict__ wf3,
              const float* __restrict__ b3, const float* __restrict__ g3,
              const float* __restrict__ a3,
              float* __restrict__ out) {
    __shared__ u64 sa[128];
    __shared__ u64 sp1[16];
    __shared__ u64 sp2[16];
    int b = blockIdx.x;
    int t = threadIdx.x;
    if (t < 128) sa[t] = abits[(size_t)b * 128 + t];
    __syncthreads();
    {
        int d = 0;
#pragma unroll 16
        for (int i = 0; i < 128; ++i)
            d += __popcll(sa[i] ^ wf1T[(size_t)i * 1024 + t]);
        double isum = (double)(8192 - 2 * d);
        double v = (isum + (double)b1[t]) * (double)g1[t] + (double)a1[t];
        u64 m = __ballot(v > 0.0);
        if ((t & 63) == 0) sp1[t >> 6] = m;
    }
    __syncthreads();
    {
        int d = 0;
#pragma unroll
        for (int i = 0; i < 16; ++i)
            d += __popcll(sp1[i] ^ wf2T[(size_t)i * 1024 + t]);
        double isum = (double)(1024 - 2 * d);
        double v = (isum + (double)b2[t]) * (double)g2[t] + (double)a2[t];
        u64 m = __ballot(v > 0.0);
        if ((t & 63) == 0) sp2[t >> 6] = m;
    }
    __syncthreads();
    if (t < 10) {
        int d = 0;
#pragma unroll
        for (int i = 0; i < 16; ++i)
            d += __popcll(sp2[i] ^ wf3[t * 16 + i]);
        double isum = (double)(1024 - 2 * d);
        out[b * 10 + t] = (float)((isum + (double)b3[t]) * (double)g3[t] + (double)a3[t]);
    }
}

// ===========================================================================

extern "C" void kernel_launch(void* const* d_in, const int* in_sizes, int n_in,
                              void* d_out, int out_size, void* d_ws, size_t ws_size,
                              hipStream_t stream) {
    const float* x       = (const float*)d_in[0];
    const float* conv1_w = (const float*)d_in[1];
    const float* conv1_b = (const float*)d_in[2];
    const float* s_w[5]  = {(const float*)d_in[3], (const float*)d_in[6], (const float*)d_in[9],
                            (const float*)d_in[12], (const float*)d_in[15]};
    const float* s_b[5]  = {(const float*)d_in[4], (const float*)d_in[7], (const float*)d_in[10],
                            (const float*)d_in[13], (const float*)d_in[16]};
    const float* s_a[5]  = {(const float*)d_in[5], (const float*)d_in[8], (const float*)d_in[11],
                            (const float*)d_in[14], (const float*)d_in[17]};
    const float* bn_g[6], *bn_b[6];
    for (int i = 0; i < 6; ++i) { bn_g[i] = (const float*)d_in[18 + 2 * i]; bn_b[i] = (const float*)d_in[19 + 2 * i]; }
    const float* fc1_w = (const float*)d_in[30]; const float* fc1_b = (const float*)d_in[31];
    const float* fc2_w = (const float*)d_in[32]; const float* fc2_b = (const float*)d_in[33];
    const float* fc3_w = (const float*)d_in[34]; const float* fc3_b = (const float*)d_in[35];
    const float* fbn_g[3], *fbn_b[3];
    for (int i = 0; i < 3; ++i) { fbn_g[i] = (const float*)d_in[36 + 2 * i]; fbn_b[i] = (const float*)d_in[37 + 2 * i]; }

    // ---- workspace carve-up -------------------------------------------------
    size_t off = 0;
    auto alloc = [&](size_t bytes) { off = (off + 255) & ~(size_t)255; size_t o = off; off += bytes; return o; };
    char* ws = (char*)d_ws;
    size_t o_apA  = alloc(1048576);
    size_t o_apB  = alloc(1048576);
    size_t o_wlut = alloc((size_t)35712 * 4 * 8);
    size_t o_cz   = alloc((size_t)1664 * 8);
    size_t o_wf1  = alloc((size_t)1024 * 128 * 8);
    size_t o_wf2  = alloc((size_t)1024 * 16 * 8);
    size_t o_wf3  = alloc((size_t)160 * 8);
    const int fragcnt[3] = {288, 1152, 4608};     // s2, s4, s6
    size_t o_wbf[3];
    for (int i = 0; i < 3; ++i) o_wbf[i] = alloc((size_t)fragcnt[i] * 1024);
    if (off > ws_size) return;

    u64* apA = (u64*)(ws + o_apA);
    u64* apB = (u64*)(ws + o_apB);
    u64* wlut = (u64*)(ws + o_wlut);
    double* czbuf = (double*)(ws + o_cz);
    u64* wf1T = (u64*)(ws + o_wf1);
    u64* wf2T = (u64*)(ws + o_wf2);
    u64* wf3 = (u64*)(ws + o_wf3);
    ushort* wbf[3];
    for (int i = 0; i < 3; ++i) wbf[i] = (ushort*)(ws + o_wbf[i]);

    const int rowoff[5] = {0, 1152, 3456, 8064, 17280};
    const int czoff[5]  = {0, 128, 384, 640, 1152};
    const int sS[5]     = {9, 9, 18, 18, 36};
    const int sCout[5]  = {128, 256, 256, 512, 512};
    const double sYsz[5] = {8388608.0, 4194304.0, 4194304.0, 2097152.0, 2097152.0};

    // ---- one prep kernel ---------------------------------------------------
    PrepArgs PA;
    const int scnt[5] = {2304, 4608, 9216, 18432, 36864};
    int totw = 0;
    for (int i = 0; i < 5; ++i) {
        PA.w[i] = s_w[i];
        PA.out[i] = wlut + (size_t)rowoff[i] * 4;
        PA.cnt[i] = scnt[i];
        PA.mode[i] = 1;
        totw += scnt[i];
    }
    PA.w[5] = fc2_w; PA.out[5] = wf2T; PA.cnt[5] = 1024 * 16; PA.mode[5] = 2; totw += 1024 * 16;
    PA.w[6] = fc3_w; PA.out[6] = wf3;  PA.cnt[6] = 160;       PA.mode[6] = 0; totw += 160;
    PA.fc1w = fc1_w; PA.fc1T = wf1T;
    for (int i = 0; i < 5; ++i) {
        PA.alpha[i] = s_a[i]; PA.bias[i] = s_b[i];
        PA.loff[i] = rowoff[i]; PA.lCout[i] = sCout[i];
        PA.gq[i] = 1.0 / sqrt(sYsz[i] * 3.0);
        PA.czoff[i] = czoff[i]; PA.czS[i] = sS[i];
    }
    PA.wlut = wlut; PA.czv = czbuf;
    const int msidx[3] = {0, 2, 4};
    int mpre = 0;
    for (int i = 0; i < 3; ++i) {
        PA.msw[i] = s_w[msidx[i]];
        PA.mwbf[i] = wbf[i];
        PA.mCout[i] = sCout[msidx[i]];
        PA.mS[i] = sS[msidx[i]];
        PA.mtoff[i] = mpre;
        mpre += fragcnt[i] * 64;
    }
    PA.R1 = totw * 64;                  // 87968*64
    PA.R2 = PA.R1 + 1024 * 8 * 64;
    PA.R3 = PA.R2 + 35712;
    PA.R4 = PA.R3 + 1664;
    PA.R5 = PA.R4 + mpre;               // + 387072
    k_prep<<<(PA.R5 + 255) / 256, 256, 0, stream>>>(PA);

    // ---- conv1 + bn1 -> signs (apA: [64][1][32][32][2]) --------------------
    k_conv1<<<64 * 32, 128, 0, stream>>>(x, conv1_w, conv1_b, bn_g[0], bn_b[0], apA);

    // ---- stages ------------------------------------------------------------
    // s2 (MFMA): 128->128 @32x32 pool -> apB
    k_stage_m<1, 32, 32, 128><<<64 * 16 * 1, 512, 0, stream>>>(
        apA, wbf[0], wlut + (size_t)rowoff[0] * 4, czbuf + czoff[0], bn_g[1], bn_b[1], apB);
    // s3 (VALU): 128->256 @16x16 -> apA
    k_stage_v<1, 1, 16, 16, 256, 256, 1, 8><<<64 * 16 * 2, 256, 0, stream>>>(
        apB, wlut + (size_t)rowoff[1] * 4, czbuf + czoff[1], bn_g[2], bn_b[2], apA);
    // s4 (MFMA): 256->256 @16x16 pool -> apB
    k_stage_m<2, 16, 16, 256><<<64 * 8 * 2, 512, 0, stream>>>(
        apA, wbf[1], wlut + (size_t)rowoff[2] * 4, czbuf + czoff[2], bn_g[3], bn_b[3], apB);
    // s5 (VALU): 256->512 @8x8 -> apA
    k_stage_v<1, 2, 8, 8, 512, 256, 1, 4><<<64 * 8 * 2 * 2, 256, 0, stream>>>(
        apB, wlut + (size_t)rowoff[3] * 4, czbuf + czoff[3], bn_g[4], bn_b[4], apA);
    // s6 (MFMA): 512->512 @8x8 pool -> apB (fc input bits)
    k_stage_m<4, 8, 8, 512><<<64 * 4 * 4, 512, 0, stream>>>(
        apA, wbf[2], wlut + (size_t)rowoff[4] * 4, czbuf + czoff[4], bn_g[5], bn_b[5], apB);

    // ---- classifier --------------------------------------------------------
    k_fc_all<<<64, 1024, 0, stream>>>(apB, wf1T, fc1_b, fbn_g[0], fbn_b[0],
                                      wf2T, fc2_b, fbn_g[1], fbn_b[1],
                                      wf3, fc3_b, fbn_g[2], fbn_b[2],
                                      (float*)d_out);
}